// Round 10
// baseline (14011.703 us; speedup 1.0000x reference)
//
#include <hip/hip_runtime.h>

typedef unsigned short u16;
typedef unsigned int   u32;
typedef __attribute__((ext_vector_type(8))) __bf16 bf16x8;
typedef __attribute__((ext_vector_type(4))) float  f32x4;

#define T_STEPS 256
#define BATCH   512
#define RB      16
#define NBLK    32

__device__ __forceinline__ u16 f2b(float f){
  u32 x = __float_as_uint(f);
  return (u16)((x + 0x7fffu + ((x >> 16) & 1u)) >> 16);
}
__device__ __forceinline__ float sigm_f(float x){ return 1.f/(1.f + __expf(-x)); }
__device__ __forceinline__ float tanh_f(float x){
  x = fminf(15.f, fmaxf(-15.f, x));
  float e = __expf(2.f*x);
  return (e - 1.f)/(e + 1.f);
}
__device__ __forceinline__ f32x4 MF(bf16x8 a, bf16x8 b, f32x4 c){
  return __builtin_amdgcn_mfma_f32_16x16x32_bf16(a, b, c, 0, 0, 0);
}

// MFMA 16x16x32 bf16 lane maps (HW-verified m89):
//   A: row=lane&15, k=(lane>>4)*8+j ; B: col=lane&15 ; D: col=lane&15, row=(lane>>4)*4+reg
__device__ __forceinline__ bf16x8 frA(const u16* buf, int l, int kc, int RS){
  int r = l & 15;
  int byte = r*RS + kc*64 + ((l >> 4) << 4);
  byte ^= (r & 7) << 4;
  return *(const bf16x8*)((const char*)buf + byte);
}
__device__ __forceinline__ void st16(u16* buf, int r, int c, u16 v, int RS){
  int byte = r*RS + c*2; byte ^= (r & 7) << 4;
  *(u16*)((char*)buf + byte) = v;
}
__device__ __forceinline__ void st16x4(u16* buf, int r, int c, ushort4 v, int RS){
  int byte = r*RS + c*2; byte ^= (r & 7) << 4;   // c%4==0 -> 8B aligned, XOR keeps it
  *(ushort4*)((char*)buf + byte) = v;
}
// fragment-packed weights: [nt][kt][lane][8] bf16, one 16B load/lane
__device__ __forceinline__ bf16x8 frB(const u16* pk, int nt, int kt, int KT, int l){
  return *(const bf16x8*)(pk + ((((nt*KT + kt) << 6) + l) << 3));
}

// f32 src -> bf16 fragment-packed dst (verified round 9)
__global__ void pack_w(const float* __restrict__ src, u16* __restrict__ dst,
                       int Ksrc, int N, int ktOff, int KT)
{
  int i = blockIdx.x*256 + threadIdx.x;
  if (i >= Ksrc*N) return;
  int j = i & 7, l = (i >> 3) & 63, p = i >> 9;
  int nkt = Ksrc >> 5;
  int kt = p % nkt, nt = p / nkt;
  int k = (kt << 5) + ((l >> 4) << 3) + j;
  int n = (nt << 4) + (l & 15);
  dst[(((nt*KT + ktOff + kt) << 6) + l)*8 + j] = f2b(src[(size_t)k*N + n]);
}

__global__ void pack_bias(const float* Wb, const float* Ub, const float* Vb,
                          const float* a1, const float* a2,
                          const float* e10, const float* e20,
                          const float* e11, const float* e21, float* bout)
{
  int i = blockIdx.x*256 + threadIdx.x;
  if (i >= 2688) return;
  float v;
  if      (i < 512)  v = Wb[i];
  else if (i < 1024) { int n = i - 512; v = Wb[n] + Ub[n] + Vb[n]; }
  else if (i < 1152) v = a1[i - 1024];
  else if (i < 2176) v = a2[i - 1152];
  else if (i < 2304) v = e10[i - 2176];
  else if (i < 2432) v = e10 == e20 ? 0.f : e20[i - 2304];
  else if (i < 2560) v = e11[i - 2432];
  else               v = e21[i - 2560];
  bout[i] = v;
}

// 32 blocks x 1024 threads; block owns batch rows [b*16, b*16+16) (full M=16 tiles).
__global__ __launch_bounds__(1024) void marn_mfma2(
  const float* __restrict__ eeg, const float* __restrict__ eog,
  const u16* __restrict__ UVWt, const u16* __restrict__ A1t,
  const u16* __restrict__ A2t,  const u16* __restrict__ D10t,
  const u16* __restrict__ D20t, const u16* __restrict__ D11t,
  const u16* __restrict__ D21t, const float* __restrict__ bias,
  float* __restrict__ out)
{
  __shared__ u16  aS1[2][16*384];   // [x|h|z] per mod, RS=768   (24.0 KB)
  __shared__ u16  aS2a[16*256];     // [h0|h1], RS=512           ( 8.0 KB)
  __shared__ u16  aS2b[16*128];     // y, RS=256                 ( 4.0 KB)
  __shared__ u16  aS3a[2][16*512];  // att per mod, RS=1024      (32.0 KB)
  __shared__ u16  aS3b[2][16*128];  // u per mod, RS=256         ( 8.0 KB)
  __shared__ float hS[2][16][128];  // h f32                     (16.0 KB)
  __shared__ float bsh[2688];       //                           (10.5 KB)

  const int tid = threadIdx.x;
  const int w = tid >> 6, l = tid & 63;
  const int hi = l >> 4, li = l & 15;
  const int r0 = blockIdx.x * RB;

  for (int i = tid; i < 2688; i += 1024) bsh[i] = bias[i];
  for (int i = tid; i < 2*16*384; i += 1024) ((u16*)aS1)[i] = 0;  // h,z zero at t=0
  float cst[2][4] = {{0,0,0,0},{0,0,0,0}};        // c-state (waves 0-7)

  // x prefetch: one float4 per thread
  const int xi = tid << 2;
  const int xm = xi >> 11, xr_ = (xi >> 7) & 15, xc = xi & 127;
  const float* xsrc = (xm ? eog : eeg) + ((size_t)(r0 + xr_))*128 + xc;
  float4 xr = *(const float4*)xsrc;
  __syncthreads();

  const int mod3 = w >> 3, nt3 = w & 7;
  const u16* Dt1 = mod3 ? D11t : D10t;
  const u16* Dt2 = mod3 ? D21t : D20t;
  const float* e1f = bsh + (mod3 ? 2432 : 2176);
  const float* e2f = bsh + (mod3 ? 2560 : 2304);

  for (int t = 0; t < T_STEPS; ++t){
    // ---- S0: stage prefetched x (bf16) ----
    {
      ushort4 v;
      v.x = f2b(xr.x); v.y = f2b(xr.y); v.z = f2b(xr.z); v.w = f2b(xr.w);
      st16x4(&aS1[xm][0], xr_, xc, v, 768);
    }
    __syncthreads();                               // A
    if (t + 1 < T_STEPS)
      xr = *(const float4*)(xsrc + (size_t)(t + 1)*BATCH*128);

    // ---- S1 A-frag read (waves 0-7; all read the same 24 frags) ----
    bf16x8 a0[12], a1[12];
    if (w < 8){
      #pragma unroll
      for (int kc = 0; kc < 12; ++kc){
        a0[kc] = frA(&aS1[0][0], l, kc, 768);
        a1[kc] = frA(&aS1[1][0], l, kc, 768);
      }
    }
    __syncthreads();                               // A2 (reads done before h-writes)

    // ---- S1: gates GEMM + in-register LSTHM update ----
    if (w < 8){
      f32x4 ac0[4] = {{0,0,0,0},{0,0,0,0},{0,0,0,0},{0,0,0,0}};
      f32x4 ac1[4] = {{0,0,0,0},{0,0,0,0},{0,0,0,0},{0,0,0,0}};
      #pragma unroll
      for (int kc = 0; kc < 12; ++kc){
        #pragma unroll
        for (int g = 0; g < 4; ++g){
          bf16x8 b = frB(UVWt, w + 8*g, kc, 12, l);
          ac0[g] = MF(a0[kc], b, ac0[g]);
          ac1[g] = MF(a1[kc], b, ac1[g]);
        }
      }
      const float* bg = bsh + (t == 0 ? 0 : 512);
      const int col = w*16 + li;
      #pragma unroll
      for (int jr = 0; jr < 4; ++jr){
        const int row = hi*4 + jr;
        {
          float f  = sigm_f(ac0[0][jr] + bg[col]);
          float ii = sigm_f(ac0[1][jr] + bg[128+col]);
          float o  = sigm_f(ac0[2][jr] + bg[256+col]);
          float ch = tanh_f(ac0[3][jr] + bg[384+col]);
          cst[0][jr] = f*cst[0][jr] + ii*ch;
          float hn = tanh_f(cst[0][jr])*o;
          st16(&aS1[0][0], row, 128 + col, f2b(hn), 768);
          st16(aS2a, row, col, f2b(hn), 512);
          hS[0][row][col] = hn;
        }
        {
          float f  = sigm_f(ac1[0][jr] + bg[col]);
          float ii = sigm_f(ac1[1][jr] + bg[128+col]);
          float o  = sigm_f(ac1[2][jr] + bg[256+col]);
          float ch = tanh_f(ac1[3][jr] + bg[384+col]);
          cst[1][jr] = f*cst[1][jr] + ii*ch;
          float hn = tanh_f(cst[1][jr])*o;
          st16(&aS1[1][0], row, 128 + col, f2b(hn), 768);
          st16(aS2a, row, 128 + col, f2b(hn), 512);
          hS[1][row][col] = hn;
        }
      }
    }
    __syncthreads();                               // B

    // ---- S2a: y = tanh([h0|h1]@A1 + a1)  (waves 8-15) ----
    if (w >= 8){
      const int nt = w - 8;
      f32x4 acc = {0,0,0,0};
      #pragma unroll
      for (int kc = 0; kc < 8; ++kc)
        acc = MF(frA(aS2a, l, kc, 512), frB(A1t, nt, kc, 8, l), acc);
      const int col = nt*16 + li;
      #pragma unroll
      for (int jr = 0; jr < 4; ++jr)
        st16(aS2b, hi*4 + jr, col, f2b(tanh_f(acc[jr] + bsh[1024 + col])), 256);
    }
    __syncthreads();                               // C

    // ---- S2b + SM: logits in-register, 4-way softmax, att ----
    {
      bf16x8 yf[4];
      #pragma unroll
      for (int kc = 0; kc < 4; ++kc) yf[kc] = frA(aS2b, l, kc, 256);
      f32x4 q0 = {0,0,0,0}, q1 = {0,0,0,0}, q2 = {0,0,0,0}, q3 = {0,0,0,0};
      #pragma unroll
      for (int kc = 0; kc < 4; ++kc){
        q0 = MF(yf[kc], frB(A2t, w,      kc, 4, l), q0);
        q1 = MF(yf[kc], frB(A2t, w + 16, kc, 4, l), q1);
        q2 = MF(yf[kc], frB(A2t, w + 32, kc, 4, l), q2);
        q3 = MF(yf[kc], frB(A2t, w + 48, kc, 4, l), q3);
      }
      const int g = w*16 + li;
      const float* a2f = bsh + 1152;
      #pragma unroll
      for (int jr = 0; jr < 4; ++jr){
        const int row = hi*4 + jr;
        float v0 = q0[jr] + a2f[g];
        float v1 = q1[jr] + a2f[256 + g];
        float v2 = q2[jr] + a2f[512 + g];
        float v3 = q3[jr] + a2f[768 + g];
        float mx = fmaxf(fmaxf(v0,v1), fmaxf(v2,v3));
        float e0 = __expf(v0-mx), e1 = __expf(v1-mx);
        float e2 = __expf(v2-mx), e3 = __expf(v3-mx);
        float inv = 1.f/(e0+e1+e2+e3);
        float h0v = hS[0][row][g & 127], h1v = hS[1][row][g & 127];
        st16(&aS3a[0][0], row, g,       f2b(e0*inv*h0v), 1024);
        st16(&aS3a[0][0], row, 256 + g, f2b(e1*inv*h0v), 1024);
        st16(&aS3a[1][0], row, g,       f2b(e2*inv*h1v), 1024);
        st16(&aS3a[1][0], row, 256 + g, f2b(e3*inv*h1v), 1024);
      }
    }
    __syncthreads();                               // D

    // ---- S3a: u = tanh(att@D1 + e1) ----
    {
      f32x4 acc = {0,0,0,0};
      #pragma unroll
      for (int kc = 0; kc < 16; ++kc)
        acc = MF(frA(&aS3a[mod3][0], l, kc, 1024), frB(Dt1, nt3, kc, 16, l), acc);
      const int col = nt3*16 + li;
      #pragma unroll
      for (int jr = 0; jr < 4; ++jr)
        st16(&aS3b[mod3][0], hi*4 + jr, col, f2b(tanh_f(acc[jr] + e1f[col])), 256);
    }
    __syncthreads();                               // E

    // ---- S3b: z = u@D2 + e2 ; out (f32) + z feedback (bf16) ----
    {
      f32x4 acc = {0,0,0,0};
      #pragma unroll
      for (int kc = 0; kc < 4; ++kc)
        acc = MF(frA(&aS3b[mod3][0], l, kc, 256), frB(Dt2, nt3, kc, 4, l), acc);
      const int col = nt3*16 + li;
      #pragma unroll
      for (int jr = 0; jr < 4; ++jr){
        const int row = hi*4 + jr;
        float z = acc[jr] + e2f[col];
        out[((size_t)t*BATCH + r0 + row)*256 + mod3*128 + col] = z;
        st16(&aS1[mod3][0], row, 256 + col, f2b(z), 768);
      }
    }
    __syncthreads();                               // F
  }
}

extern "C" void kernel_launch(void* const* d_in, const int* in_sizes, int n_in,
                              void* d_out, int out_size, void* d_ws, size_t ws_size,
                              hipStream_t stream)
{
  const float* eeg = (const float*)d_in[0];
  const float* eog = (const float*)d_in[1];
  const float* Ww  = (const float*)d_in[2];
  const float* Wb  = (const float*)d_in[3];
  const float* Uw  = (const float*)d_in[4];
  const float* Ub  = (const float*)d_in[5];
  const float* Vw  = (const float*)d_in[6];
  const float* Vb  = (const float*)d_in[7];
  const float* A1  = (const float*)d_in[8];
  const float* a1  = (const float*)d_in[9];
  const float* A2  = (const float*)d_in[10];
  const float* a2  = (const float*)d_in[11];
  const float* D10 = (const float*)d_in[12];
  const float* e10 = (const float*)d_in[13];
  const float* D20 = (const float*)d_in[14];
  const float* e20 = (const float*)d_in[15];
  const float* D11 = (const float*)d_in[16];
  const float* e11 = (const float*)d_in[17];
  const float* D21 = (const float*)d_in[18];
  const float* e21 = (const float*)d_in[19];

  char* ws = (char*)d_ws;
  u16*  UVWt = (u16*)(ws);                  // 393216 B
  u16*  A1t  = (u16*)(ws + 393216);         // 65536 B
  u16*  A2t  = (u16*)(ws + 458752);         // 262144 B
  u16*  D10t = (u16*)(ws + 720896);         // 131072 B
  u16*  D20t = (u16*)(ws + 851968);         // 32768 B
  u16*  D11t = (u16*)(ws + 884736);         // 131072 B
  u16*  D21t = (u16*)(ws + 1015808);        // 32768 B
  float* bias = (float*)(ws + 1048576);     // 2688 f32

  auto nb = [](int n){ return dim3((unsigned)((n + 255)/256)); };
  pack_w<<<nb(65536),  256, 0, stream>>>(Ww,  UVWt, 128, 512,  0, 12);
  pack_w<<<nb(65536),  256, 0, stream>>>(Uw,  UVWt, 128, 512,  4, 12);
  pack_w<<<nb(65536),  256, 0, stream>>>(Vw,  UVWt, 128, 512,  8, 12);
  pack_w<<<nb(32768),  256, 0, stream>>>(A1,  A1t,  256, 128,  0, 8);
  pack_w<<<nb(131072), 256, 0, stream>>>(A2,  A2t,  128, 1024, 0, 4);
  pack_w<<<nb(65536),  256, 0, stream>>>(D10, D10t, 512, 128,  0, 16);
  pack_w<<<nb(16384),  256, 0, stream>>>(D20, D20t, 128, 128,  0, 4);
  pack_w<<<nb(65536),  256, 0, stream>>>(D11, D11t, 512, 128,  0, 16);
  pack_w<<<nb(16384),  256, 0, stream>>>(D21, D21t, 128, 128,  0, 4);
  pack_bias<<<nb(2688), 256, 0, stream>>>(Wb, Ub, Vb, a1, a2, e10, e20, e11, e21, bias);

  marn_mfma2<<<NBLK, 1024, 0, stream>>>(eeg, eog, UVWt, A1t, A2t,
                                        D10t, D20t, D11t, D21t, bias, (float*)d_out);
}

// Round 12
// 9823.538 us; speedup vs baseline: 1.4263x; 1.4263x over previous
//
#include <hip/hip_runtime.h>

typedef unsigned short u16;
typedef unsigned int   u32;
typedef __attribute__((ext_vector_type(8))) __bf16 bf16x8;
typedef __attribute__((ext_vector_type(4))) float  f32x4;

#define T_STEPS 256
#define BATCH   512
#define RB      16
#define NBLK    32

__device__ __forceinline__ float b2f(u16 u){
  union { u32 i; float f; } v; v.i = ((u32)u) << 16; return v.f;
}
__device__ __forceinline__ u16 f2b(float f){
  u32 x = __float_as_uint(f);
  return (u16)((x + 0x7fffu + ((x >> 16) & 1u)) >> 16);
}
__device__ __forceinline__ float sigm_f(float x){ return 1.f/(1.f + __expf(-x)); }
__device__ __forceinline__ float tanh_f(float x){
  x = fminf(15.f, fmaxf(-15.f, x));
  float e = __expf(2.f*x);
  return (e - 1.f)/(e + 1.f);
}
__device__ __forceinline__ f32x4 MF(bf16x8 a, bf16x8 b, f32x4 c){
  return __builtin_amdgcn_mfma_f32_16x16x32_bf16(a, b, c, 0, 0, 0);
}

// MFMA 16x16x32 bf16 lane maps (HW-verified m89):
//   A: row=lane&15, k=(lane>>4)*8+j ; B: col=lane&15 ; D: col=lane&15, row=(lane>>4)*4+reg
__device__ __forceinline__ bf16x8 frA(const u16* buf, int l, int kc, int RS){
  int r = l & 15;
  int byte = r*RS + kc*64 + ((l >> 4) << 4);
  byte ^= (r & 7) << 4;
  return *(const bf16x8*)((const char*)buf + byte);
}
__device__ __forceinline__ void st16(u16* buf, int r, int c, u16 v, int RS){
  int byte = r*RS + c*2; byte ^= (r & 7) << 4;
  *(u16*)((char*)buf + byte) = v;
}
__device__ __forceinline__ float ld16f(const u16* buf, int r, int c, int RS){
  int byte = r*RS + c*2; byte ^= (r & 7) << 4;
  return b2f(*(const u16*)((const char*)buf + byte));
}
__device__ __forceinline__ void st16x4(u16* buf, int r, int c, ushort4 v, int RS){
  int byte = r*RS + c*2; byte ^= (r & 7) << 4;   // c%4==0 -> 8B aligned, XOR keeps it
  *(ushort4*)((char*)buf + byte) = v;
}
// fragment-packed weights: [nt][kt][lane][8] bf16, one 16B load/lane
__device__ __forceinline__ bf16x8 frB(const u16* pk, int nt, int kt, int KT, int l){
  return *(const bf16x8*)(pk + ((((nt*KT + kt) << 6) + l) << 3));
}

// f32 src -> bf16 fragment-packed dst (verified round 9)
__global__ void pack_w(const float* __restrict__ src, u16* __restrict__ dst,
                       int Ksrc, int N, int ktOff, int KT)
{
  int i = blockIdx.x*256 + threadIdx.x;
  if (i >= Ksrc*N) return;
  int j = i & 7, l = (i >> 3) & 63, p = i >> 9;
  int nkt = Ksrc >> 5;
  int kt = p % nkt, nt = p / nkt;
  int k = (kt << 5) + ((l >> 4) << 3) + j;
  int n = (nt << 4) + (l & 15);
  dst[(((nt*KT + ktOff + kt) << 6) + l)*8 + j] = f2b(src[(size_t)k*N + n]);
}

__global__ void pack_bias(const float* Wb, const float* Ub, const float* Vb,
                          const float* a1, const float* a2,
                          const float* e10, const float* e20,
                          const float* e11, const float* e21, float* bout)
{
  int i = blockIdx.x*256 + threadIdx.x;
  if (i >= 2688) return;
  float v;
  if      (i < 512)  v = Wb[i];
  else if (i < 1024) { int n = i - 512; v = Wb[n] + Ub[n] + Vb[n]; }
  else if (i < 1152) v = a1[i - 1024];
  else if (i < 2176) v = a2[i - 1152];
  else if (i < 2304) v = e10[i - 2176];
  else if (i < 2432) v = e20[i - 2304];
  else if (i < 2560) v = e11[i - 2432];
  else               v = e21[i - 2560];
  bout[i] = v;
}

// 32 blocks x 1024 threads; block owns batch rows [b*16, b*16+16).
__global__ __launch_bounds__(1024, 4) void marn_mfma4(
  const float* __restrict__ eeg, const float* __restrict__ eog,
  const u16* __restrict__ UVWt, const u16* __restrict__ A1t,
  const u16* __restrict__ A2t,  const u16* __restrict__ D10t,
  const u16* __restrict__ D20t, const u16* __restrict__ D11t,
  const u16* __restrict__ D21t, const float* __restrict__ bias,
  float* __restrict__ out)
{
  __shared__ u16  aS1[2][16*384];   // [x|h|z] per mod, RS=768   (24.0 KB)
  __shared__ u16  aS2a[16*256];     // [h0|h1], RS=512           ( 8.0 KB)
  __shared__ u16  aS2b[16*128];     // y, RS=256                 ( 4.0 KB)
  __shared__ u16  aS3a[2][16*512];  // att per mod, RS=1024      (32.0 KB)
  __shared__ u16  aS3b[2][16*128];  // u per mod, RS=256         ( 8.0 KB)
  __shared__ float bsh[2688];       //                           (10.5 KB)

  const int tid = threadIdx.x;
  const int w = tid >> 6, l = tid & 63;
  const int hi = l >> 4, li = l & 15;
  const int r0 = blockIdx.x * RB;

  for (int i = tid; i < 2688; i += 1024) bsh[i] = bias[i];
  for (int i = tid; i < 2*16*384; i += 1024) ((u16*)aS1)[i] = 0;  // h,z zero at t=0
  float cst[2][4] = {{0,0,0,0},{0,0,0,0}};        // c-state (waves 0-7)

  // x(0) prefetch: one float4 per thread
  const int xi = tid << 2;
  const int xm = xi >> 11, xr_ = (xi >> 7) & 15, xc = xi & 127;
  const float* xsrc = (xm ? eog : eeg) + ((size_t)(r0 + xr_))*128 + xc;
  f32x4 xr = __builtin_nontemporal_load((const f32x4*)xsrc);
  __syncthreads();                 // RACE FIX (R11 bug): init visible before x-stage
  {
    ushort4 v;
    v.x = f2b(xr[0]); v.y = f2b(xr[1]); v.z = f2b(xr[2]); v.w = f2b(xr[3]);
    st16x4(&aS1[xm][0], xr_, xc, v, 768);
  }
  __syncthreads();                 // x(0) staged

  const int mod3 = w >> 3, nt3 = w & 7;
  const u16* Dt1 = mod3 ? D11t : D10t;
  const u16* Dt2 = mod3 ? D21t : D20t;
  const float* e1f = bsh + (mod3 ? 2432 : 2176);
  const float* e2f = bsh + (mod3 ? 2560 : 2304);

  for (int t = 0; t < T_STEPS; ++t){
    // ---- S1: gates GEMM (waves 0-7), streaming A-frags per kc ----
    f32x4 ac0[4] = {{0,0,0,0},{0,0,0,0},{0,0,0,0},{0,0,0,0}};
    f32x4 ac1[4] = {{0,0,0,0},{0,0,0,0},{0,0,0,0},{0,0,0,0}};
    if (w < 8){
      #pragma unroll
      for (int kc = 0; kc < 12; ++kc){
        bf16x8 fa0 = frA(&aS1[0][0], l, kc, 768);
        bf16x8 fa1 = frA(&aS1[1][0], l, kc, 768);
        #pragma unroll
        for (int g = 0; g < 4; ++g){
          bf16x8 b = frB(UVWt, w + 8*g, kc, 12, l);
          ac0[g] = MF(fa0, b, ac0[g]);
          ac1[g] = MF(fa1, b, ac1[g]);
        }
      }
    }
    __syncthreads();                               // B1: S1 LDS reads done

    // ---- S1ep: in-register LSTHM cell update (waves 0-7) ----
    if (w < 8){
      const float* bg = bsh + (t == 0 ? 0 : 512);
      const int col = w*16 + li;
      #pragma unroll
      for (int jr = 0; jr < 4; ++jr){
        const int row = hi*4 + jr;
        {
          float f  = sigm_f(ac0[0][jr] + bg[col]);
          float ii = sigm_f(ac0[1][jr] + bg[128+col]);
          float o  = sigm_f(ac0[2][jr] + bg[256+col]);
          float ch = tanh_f(ac0[3][jr] + bg[384+col]);
          cst[0][jr] = f*cst[0][jr] + ii*ch;
          u16 hb = f2b(tanh_f(cst[0][jr])*o);
          st16(&aS1[0][0], row, 128 + col, hb, 768);
          st16(aS2a, row, col, hb, 512);
        }
        {
          float f  = sigm_f(ac1[0][jr] + bg[col]);
          float ii = sigm_f(ac1[1][jr] + bg[128+col]);
          float o  = sigm_f(ac1[2][jr] + bg[256+col]);
          float ch = tanh_f(ac1[3][jr] + bg[384+col]);
          cst[1][jr] = f*cst[1][jr] + ii*ch;
          u16 hb = f2b(tanh_f(cst[1][jr])*o);
          st16(&aS1[1][0], row, 128 + col, hb, 768);
          st16(aS2a, row, 128 + col, hb, 512);
        }
      }
    }
    __syncthreads();                               // B2: h visible

    // ---- S2a: y = tanh([h0|h1]@A1 + a1) (waves 8-15) ----
    if (w >= 8){
      const int nt = w - 8;
      f32x4 acc = {0,0,0,0};
      #pragma unroll
      for (int kc = 0; kc < 8; ++kc)
        acc = MF(frA(aS2a, l, kc, 512), frB(A1t, nt, kc, 8, l), acc);
      const int col = nt*16 + li;
      #pragma unroll
      for (int jr = 0; jr < 4; ++jr)
        st16(aS2b, hi*4 + jr, col, f2b(tanh_f(acc[jr] + bsh[1024 + col])), 256);
    }
    // all waves: prefetch first half of their A2 B-frags (independent of LDS)
    bf16x8 a2pf[8];
    #pragma unroll
    for (int q = 0; q < 2; ++q)
      #pragma unroll
      for (int kc = 0; kc < 4; ++kc)
        a2pf[q*4 + kc] = frB(A2t, w + 16*q, kc, 4, l);
    __syncthreads();                               // B3: y visible

    // ---- S2b + SM: logits in-register, 4-way softmax, att ----
    // x(t+1) prefetch issued here (3 stages of latency cover)
    {
      int tn = (t + 1 < T_STEPS) ? t + 1 : t;
      xr = __builtin_nontemporal_load((const f32x4*)(xsrc + (size_t)tn*BATCH*128));
    }
    {
      bf16x8 yf[4];
      #pragma unroll
      for (int kc = 0; kc < 4; ++kc) yf[kc] = frA(aS2b, l, kc, 256);
      f32x4 q0 = {0,0,0,0}, q1 = {0,0,0,0}, q2 = {0,0,0,0}, q3 = {0,0,0,0};
      #pragma unroll
      for (int kc = 0; kc < 4; ++kc){
        q0 = MF(yf[kc], a2pf[kc],     q0);
        q1 = MF(yf[kc], a2pf[4 + kc], q1);
        q2 = MF(yf[kc], frB(A2t, w + 32, kc, 4, l), q2);
        q3 = MF(yf[kc], frB(A2t, w + 48, kc, 4, l), q3);
      }
      const int g = w*16 + li;
      const float* a2f = bsh + 1152;
      #pragma unroll
      for (int jr = 0; jr < 4; ++jr){
        const int row = hi*4 + jr;
        float v0 = q0[jr] + a2f[g];
        float v1 = q1[jr] + a2f[256 + g];
        float v2 = q2[jr] + a2f[512 + g];
        float v3 = q3[jr] + a2f[768 + g];
        float mx = fmaxf(fmaxf(v0,v1), fmaxf(v2,v3));
        float e0 = __expf(v0-mx), e1 = __expf(v1-mx);
        float e2 = __expf(v2-mx), e3 = __expf(v3-mx);
        float inv = 1.f/(e0+e1+e2+e3);
        float h0v = ld16f(aS2a, row, g & 127, 512);
        float h1v = ld16f(aS2a, row, 128 + (g & 127), 512);
        st16(&aS3a[0][0], row, g,       f2b(e0*inv*h0v), 1024);
        st16(&aS3a[0][0], row, 256 + g, f2b(e1*inv*h0v), 1024);
        st16(&aS3a[1][0], row, g,       f2b(e2*inv*h1v), 1024);
        st16(&aS3a[1][0], row, 256 + g, f2b(e3*inv*h1v), 1024);
      }
    }
    __syncthreads();                               // B4: att visible

    // ---- S3a: u = tanh(att@D1 + e1) (all 16 waves) ----
    {
      f32x4 acc = {0,0,0,0};
      #pragma unroll
      for (int kc = 0; kc < 16; ++kc)
        acc = MF(frA(&aS3a[mod3][0], l, kc, 1024), frB(Dt1, nt3, kc, 16, l), acc);
      const int col = nt3*16 + li;
      #pragma unroll
      for (int jr = 0; jr < 4; ++jr)
        st16(&aS3b[mod3][0], hi*4 + jr, col, f2b(tanh_f(acc[jr] + e1f[col])), 256);
    }
    __syncthreads();                               // B5: u visible

    // ---- S3b: z = u@D2 + e2 ; NT-store out ; z + x(t+1) into aS1 ----
    {
      f32x4 acc = {0,0,0,0};
      #pragma unroll
      for (int kc = 0; kc < 4; ++kc)
        acc = MF(frA(&aS3b[mod3][0], l, kc, 256), frB(Dt2, nt3, kc, 4, l), acc);
      const int col = nt3*16 + li;
      #pragma unroll
      for (int jr = 0; jr < 4; ++jr){
        const int row = hi*4 + jr;
        float z = acc[jr] + e2f[col];
        __builtin_nontemporal_store(z, &out[((size_t)t*BATCH + r0 + row)*256 + mod3*128 + col]);
        st16(&aS1[mod3][0], row, 256 + col, f2b(z), 768);
      }
    }
    {
      ushort4 v;
      v.x = f2b(xr[0]); v.y = f2b(xr[1]); v.z = f2b(xr[2]); v.w = f2b(xr[3]);
      st16x4(&aS1[xm][0], xr_, xc, v, 768);
    }
    __syncthreads();                               // B6: z,x visible for next S1
  }
}

extern "C" void kernel_launch(void* const* d_in, const int* in_sizes, int n_in,
                              void* d_out, int out_size, void* d_ws, size_t ws_size,
                              hipStream_t stream)
{
  const float* eeg = (const float*)d_in[0];
  const float* eog = (const float*)d_in[1];
  const float* Ww  = (const float*)d_in[2];
  const float* Wb  = (const float*)d_in[3];
  const float* Uw  = (const float*)d_in[4];
  const float* Ub  = (const float*)d_in[5];
  const float* Vw  = (const float*)d_in[6];
  const float* Vb  = (const float*)d_in[7];
  const float* A1  = (const float*)d_in[8];
  const float* a1  = (const float*)d_in[9];
  const float* A2  = (const float*)d_in[10];
  const float* a2  = (const float*)d_in[11];
  const float* D10 = (const float*)d_in[12];
  const float* e10 = (const float*)d_in[13];
  const float* D20 = (const float*)d_in[14];
  const float* e20 = (const float*)d_in[15];
  const float* D11 = (const float*)d_in[16];
  const float* e11 = (const float*)d_in[17];
  const float* D21 = (const float*)d_in[18];
  const float* e21 = (const float*)d_in[19];

  char* ws = (char*)d_ws;
  u16*  UVWt = (u16*)(ws);                  // 393216 B
  u16*  A1t  = (u16*)(ws + 393216);         // 65536 B
  u16*  A2t  = (u16*)(ws + 458752);         // 262144 B
  u16*  D10t = (u16*)(ws + 720896);         // 131072 B
  u16*  D20t = (u16*)(ws + 851968);         // 32768 B
  u16*  D11t = (u16*)(ws + 884736);         // 131072 B
  u16*  D21t = (u16*)(ws + 1015808);        // 32768 B
  float* bias = (float*)(ws + 1048576);     // 2688 f32

  auto nb = [](int n){ return dim3((unsigned)((n + 255)/256)); };
  pack_w<<<nb(65536),  256, 0, stream>>>(Ww,  UVWt, 128, 512,  0, 12);
  pack_w<<<nb(65536),  256, 0, stream>>>(Uw,  UVWt, 128, 512,  4, 12);
  pack_w<<<nb(65536),  256, 0, stream>>>(Vw,  UVWt, 128, 512,  8, 12);
  pack_w<<<nb(32768),  256, 0, stream>>>(A1,  A1t,  256, 128,  0, 8);
  pack_w<<<nb(131072), 256, 0, stream>>>(A2,  A2t,  128, 1024, 0, 4);
  pack_w<<<nb(65536),  256, 0, stream>>>(D10, D10t, 512, 128,  0, 16);
  pack_w<<<nb(16384),  256, 0, stream>>>(D20, D20t, 128, 128,  0, 4);
  pack_w<<<nb(65536),  256, 0, stream>>>(D11, D11t, 512, 128,  0, 16);
  pack_w<<<nb(16384),  256, 0, stream>>>(D21, D21t, 128, 128,  0, 4);
  pack_bias<<<nb(2688), 256, 0, stream>>>(Wb, Ub, Vb, a1, a2, e10, e20, e11, e21, bias);

  marn_mfma4<<<NBLK, 1024, 0, stream>>>(eeg, eog, UVWt, A1t, A2t,
                                        D10t, D20t, D11t, D21t, bias, (float*)d_out);
}

// Round 13
// 7106.452 us; speedup vs baseline: 1.9717x; 1.3823x over previous
//
#include <hip/hip_runtime.h>

typedef unsigned short u16;
typedef unsigned int   u32;
typedef __attribute__((ext_vector_type(8))) __bf16 bf16x8;
typedef __attribute__((ext_vector_type(4))) float  f32x4;

#define T_STEPS 256
#define BATCH   512
#define RB      16
#define NBLK    32

__device__ __forceinline__ float b2f(u16 u){
  union { u32 i; float f; } v; v.i = ((u32)u) << 16; return v.f;
}
__device__ __forceinline__ u16 f2b(float f){
  u32 x = __float_as_uint(f);
  return (u16)((x + 0x7fffu + ((x >> 16) & 1u)) >> 16);
}
__device__ __forceinline__ float sigm_f(float x){ return 1.f/(1.f + __expf(-x)); }
__device__ __forceinline__ float tanh_f(float x){
  x = fminf(15.f, fmaxf(-15.f, x));
  float e = __expf(2.f*x);
  return (e - 1.f)/(e + 1.f);
}
__device__ __forceinline__ f32x4 MF(bf16x8 a, bf16x8 b, f32x4 c){
  return __builtin_amdgcn_mfma_f32_16x16x32_bf16(a, b, c, 0, 0, 0);
}

// MFMA 16x16x32 bf16 lane maps (HW-verified m89):
//   A: row=lane&15, k=(lane>>4)*8+j ; B: col=lane&15 ; D: col=lane&15, row=(lane>>4)*4+reg
__device__ __forceinline__ bf16x8 frA(const u16* buf, int l, int kc, int RS){
  int r = l & 15;
  int byte = r*RS + kc*64 + ((l >> 4) << 4);
  byte ^= (r & 7) << 4;
  return *(const bf16x8*)((const char*)buf + byte);
}
__device__ __forceinline__ void st16(u16* buf, int r, int c, u16 v, int RS){
  int byte = r*RS + c*2; byte ^= (r & 7) << 4;
  *(u16*)((char*)buf + byte) = v;
}
__device__ __forceinline__ float ld16f(const u16* buf, int r, int c, int RS){
  int byte = r*RS + c*2; byte ^= (r & 7) << 4;
  return b2f(*(const u16*)((const char*)buf + byte));
}
__device__ __forceinline__ void st16x4(u16* buf, int r, int c, ushort4 v, int RS){
  int byte = r*RS + c*2; byte ^= (r & 7) << 4;   // c%4==0 -> 8B aligned, XOR keeps it
  *(ushort4*)((char*)buf + byte) = v;
}
// fragment-packed weights: [nt][kt][lane][8] bf16, one 16B load/lane
__device__ __forceinline__ bf16x8 frB(const u16* pk, int nt, int kt, int KT, int l){
  return *(const bf16x8*)(pk + ((((nt*KT + kt) << 6) + l) << 3));
}

// f32 src -> bf16 fragment-packed dst (verified round 9)
__global__ void pack_w(const float* __restrict__ src, u16* __restrict__ dst,
                       int Ksrc, int N, int ktOff, int KT)
{
  int i = blockIdx.x*256 + threadIdx.x;
  if (i >= Ksrc*N) return;
  int j = i & 7, l = (i >> 3) & 63, p = i >> 9;
  int nkt = Ksrc >> 5;
  int kt = p % nkt, nt = p / nkt;
  int k = (kt << 5) + ((l >> 4) << 3) + j;
  int n = (nt << 4) + (l & 15);
  dst[(((nt*KT + ktOff + kt) << 6) + l)*8 + j] = f2b(src[(size_t)k*N + n]);
}

__global__ void pack_bias(const float* Wb, const float* Ub, const float* Vb,
                          const float* a1, const float* a2,
                          const float* e10, const float* e20,
                          const float* e11, const float* e21, float* bout)
{
  int i = blockIdx.x*256 + threadIdx.x;
  if (i >= 2688) return;
  float v;
  if      (i < 512)  v = Wb[i];
  else if (i < 1024) { int n = i - 512; v = Wb[n] + Ub[n] + Vb[n]; }
  else if (i < 1152) v = a1[i - 1024];
  else if (i < 2176) v = a2[i - 1152];
  else if (i < 2304) v = e10[i - 2176];
  else if (i < 2432) v = e20[i - 2304];
  else if (i < 2560) v = e11[i - 2432];
  else               v = e21[i - 2560];
  bout[i] = v;
}

// 32 blocks x 512 threads (8 waves, 256-VGPR budget); block owns rows [b*16, b*16+16).
__global__ __launch_bounds__(512, 2) void marn_mfma5(
  const float* __restrict__ eeg, const float* __restrict__ eog,
  const u16* __restrict__ UVWt, const u16* __restrict__ A1t,
  const u16* __restrict__ A2t,  const u16* __restrict__ D10t,
  const u16* __restrict__ D20t, const u16* __restrict__ D11t,
  const u16* __restrict__ D21t, const float* __restrict__ bias,
  float* __restrict__ out)
{
  __shared__ u16  aS1[2][16*384];   // [x|h|z] per mod, RS=768   (24.0 KB)
  __shared__ u16  aS2a[16*256];     // [h0|h1], RS=512           ( 8.0 KB)
  __shared__ u16  aS2b[16*128];     // y, RS=256                 ( 4.0 KB)
  __shared__ u16  aS3a[2][16*512];  // att per mod, RS=1024      (32.0 KB)
  __shared__ u16  aS3b[2][16*128];  // u per mod, RS=256         ( 8.0 KB)
  __shared__ float bsh[2688];       //                           (10.5 KB)

  const int tid = threadIdx.x;
  const int w = tid >> 6, l = tid & 63;     // w in [0,8)
  const int hi = l >> 4, li = l & 15;
  const int r0 = blockIdx.x * RB;

  for (int i = tid; i < 2688; i += 512) bsh[i] = bias[i];
  for (int i = tid; i < 2*16*384; i += 512) ((u16*)aS1)[i] = 0;  // h,z zero at t=0
  float cst[2][4] = {{0,0,0,0},{0,0,0,0}};  // c-state: wave w cols w*16+li, rows hi*4+jr

  // x(0) prefetch: 8 u16 per thread (2 float4)
  const int xi = tid << 3;
  const int xm = xi >> 11, xrr = (xi >> 7) & 15, xc = xi & 127;
  const float* xsrc = (xm ? eog : eeg) + ((size_t)(r0 + xrr))*128 + xc;
  f32x4 xa = __builtin_nontemporal_load((const f32x4*)xsrc);
  f32x4 xb = __builtin_nontemporal_load((const f32x4*)(xsrc + 4));
  __syncthreads();                 // init visible before x-stage (R11 race fix)
  {
    ushort4 va, vb;
    va.x = f2b(xa[0]); va.y = f2b(xa[1]); va.z = f2b(xa[2]); va.w = f2b(xa[3]);
    vb.x = f2b(xb[0]); vb.y = f2b(xb[1]); vb.z = f2b(xb[2]); vb.w = f2b(xb[3]);
    st16x4(&aS1[xm][0], xrr, xc,     va, 768);
    st16x4(&aS1[xm][0], xrr, xc + 4, vb, 768);
  }
  __syncthreads();                 // x(0) staged

  for (int t = 0; t < T_STEPS; ++t){
    // ---- S1: gates GEMM (all 8 waves; wave w -> nt = w,w+8,w+16,w+24) ----
    f32x4 ac0[4] = {{0,0,0,0},{0,0,0,0},{0,0,0,0},{0,0,0,0}};
    f32x4 ac1[4] = {{0,0,0,0},{0,0,0,0},{0,0,0,0},{0,0,0,0}};
    {
      #pragma unroll
      for (int kc = 0; kc < 12; ++kc){
        bf16x8 fa0 = frA(&aS1[0][0], l, kc, 768);
        bf16x8 fa1 = frA(&aS1[1][0], l, kc, 768);
        #pragma unroll
        for (int g = 0; g < 4; ++g){
          bf16x8 b = frB(UVWt, w + 8*g, kc, 12, l);
          ac0[g] = MF(fa0, b, ac0[g]);
          ac1[g] = MF(fa1, b, ac1[g]);
        }
      }
    }
    __syncthreads();                               // B1: S1 LDS reads done

    // ---- S1ep: in-register LSTHM cell update (all waves) ----
    {
      const float* bg = bsh + (t == 0 ? 0 : 512);
      const int col = w*16 + li;
      #pragma unroll
      for (int jr = 0; jr < 4; ++jr){
        const int row = hi*4 + jr;
        {
          float f  = sigm_f(ac0[0][jr] + bg[col]);
          float ii = sigm_f(ac0[1][jr] + bg[128+col]);
          float o  = sigm_f(ac0[2][jr] + bg[256+col]);
          float ch = tanh_f(ac0[3][jr] + bg[384+col]);
          cst[0][jr] = f*cst[0][jr] + ii*ch;
          u16 hb = f2b(tanh_f(cst[0][jr])*o);
          st16(&aS1[0][0], row, 128 + col, hb, 768);
          st16(aS2a, row, col, hb, 512);
        }
        {
          float f  = sigm_f(ac1[0][jr] + bg[col]);
          float ii = sigm_f(ac1[1][jr] + bg[128+col]);
          float o  = sigm_f(ac1[2][jr] + bg[256+col]);
          float ch = tanh_f(ac1[3][jr] + bg[384+col]);
          cst[1][jr] = f*cst[1][jr] + ii*ch;
          u16 hb = f2b(tanh_f(cst[1][jr])*o);
          st16(&aS1[1][0], row, 128 + col, hb, 768);
          st16(aS2a, row, 128 + col, hb, 512);
        }
      }
    }
    __syncthreads();                               // B2: h visible

    // ---- S2a: y = tanh([h0|h1]@A1 + a1)  (wave w -> nt = w) ----
    {
      f32x4 acc = {0,0,0,0};
      #pragma unroll
      for (int kc = 0; kc < 8; ++kc)
        acc = MF(frA(aS2a, l, kc, 512), frB(A1t, w, kc, 8, l), acc);
      const int col = w*16 + li;
      #pragma unroll
      for (int jr = 0; jr < 4; ++jr)
        st16(aS2b, hi*4 + jr, col, f2b(tanh_f(acc[jr] + bsh[1024 + col])), 256);
    }
    __syncthreads();                               // B3: y visible

    // x(t+1) prefetch issued here (3 phases of latency cover)
    {
      int tn = (t + 1 < T_STEPS) ? t + 1 : t;
      xa = __builtin_nontemporal_load((const f32x4*)(xsrc + (size_t)tn*BATCH*128));
      xb = __builtin_nontemporal_load((const f32x4*)(xsrc + (size_t)tn*BATCH*128 + 4));
    }

    // ---- S2b + SM: logits (wave w -> g-blocks w, w+8), softmax, att ----
    {
      bf16x8 yf[4];
      #pragma unroll
      for (int kc = 0; kc < 4; ++kc) yf[kc] = frA(aS2b, l, kc, 256);
      const float* a2f = bsh + 1152;
      #pragma unroll
      for (int gq = 0; gq < 2; ++gq){
        const int gb = w + 8*gq;
        f32x4 q0 = {0,0,0,0}, q1 = {0,0,0,0}, q2 = {0,0,0,0}, q3 = {0,0,0,0};
        #pragma unroll
        for (int kc = 0; kc < 4; ++kc){
          q0 = MF(yf[kc], frB(A2t, gb,      kc, 4, l), q0);
          q1 = MF(yf[kc], frB(A2t, gb + 16, kc, 4, l), q1);
          q2 = MF(yf[kc], frB(A2t, gb + 32, kc, 4, l), q2);
          q3 = MF(yf[kc], frB(A2t, gb + 48, kc, 4, l), q3);
        }
        const int g = gb*16 + li;
        #pragma unroll
        for (int jr = 0; jr < 4; ++jr){
          const int row = hi*4 + jr;
          float v0 = q0[jr] + a2f[g];
          float v1 = q1[jr] + a2f[256 + g];
          float v2 = q2[jr] + a2f[512 + g];
          float v3 = q3[jr] + a2f[768 + g];
          float mx = fmaxf(fmaxf(v0,v1), fmaxf(v2,v3));
          float e0 = __expf(v0-mx), e1 = __expf(v1-mx);
          float e2 = __expf(v2-mx), e3 = __expf(v3-mx);
          float inv = 1.f/(e0+e1+e2+e3);
          float h0v = ld16f(aS2a, row, g & 127, 512);
          float h1v = ld16f(aS2a, row, 128 + (g & 127), 512);
          st16(&aS3a[0][0], row, g,       f2b(e0*inv*h0v), 1024);
          st16(&aS3a[0][0], row, 256 + g, f2b(e1*inv*h0v), 1024);
          st16(&aS3a[1][0], row, g,       f2b(e2*inv*h1v), 1024);
          st16(&aS3a[1][0], row, 256 + g, f2b(e3*inv*h1v), 1024);
        }
      }
    }
    __syncthreads();                               // B4: att visible

    // ---- S3a: u = tanh(att@D1 + e1)  (wave w -> col-block w, both mods) ----
    {
      #pragma unroll
      for (int m = 0; m < 2; ++m){
        const u16* Dt = m ? D11t : D10t;
        f32x4 acc = {0,0,0,0};
        #pragma unroll
        for (int kc = 0; kc < 16; ++kc)
          acc = MF(frA(&aS3a[m][0], l, kc, 1024), frB(Dt, w, kc, 16, l), acc);
        const int col = w*16 + li;
        const float* e1f = bsh + (m ? 2432 : 2176);
        #pragma unroll
        for (int jr = 0; jr < 4; ++jr)
          st16(&aS3b[m][0], hi*4 + jr, col, f2b(tanh_f(acc[jr] + e1f[col])), 256);
      }
    }
    __syncthreads();                               // B5: u visible

    // ---- S3b: z = u@D2 + e2 ; NT-store out ; z + x(t+1) into aS1 ----
    {
      #pragma unroll
      for (int m = 0; m < 2; ++m){
        const u16* Dt = m ? D21t : D20t;
        f32x4 acc = {0,0,0,0};
        #pragma unroll
        for (int kc = 0; kc < 4; ++kc)
          acc = MF(frA(&aS3b[m][0], l, kc, 256), frB(Dt, w, kc, 4, l), acc);
        const int col = w*16 + li;
        const float* e2f = bsh + (m ? 2560 : 2304);
        #pragma unroll
        for (int jr = 0; jr < 4; ++jr){
          const int row = hi*4 + jr;
          float z = acc[jr] + e2f[col];
          __builtin_nontemporal_store(z, &out[((size_t)t*BATCH + r0 + row)*256 + m*128 + col]);
          st16(&aS1[m][0], row, 256 + col, f2b(z), 768);
        }
      }
    }
    {
      ushort4 va, vb;
      va.x = f2b(xa[0]); va.y = f2b(xa[1]); va.z = f2b(xa[2]); va.w = f2b(xa[3]);
      vb.x = f2b(xb[0]); vb.y = f2b(xb[1]); vb.z = f2b(xb[2]); vb.w = f2b(xb[3]);
      st16x4(&aS1[xm][0], xrr, xc,     va, 768);
      st16x4(&aS1[xm][0], xrr, xc + 4, vb, 768);
    }
    __syncthreads();                               // B6: z,x visible for next S1
  }
}

extern "C" void kernel_launch(void* const* d_in, const int* in_sizes, int n_in,
                              void* d_out, int out_size, void* d_ws, size_t ws_size,
                              hipStream_t stream)
{
  const float* eeg = (const float*)d_in[0];
  const float* eog = (const float*)d_in[1];
  const float* Ww  = (const float*)d_in[2];
  const float* Wb  = (const float*)d_in[3];
  const float* Uw  = (const float*)d_in[4];
  const float* Ub  = (const float*)d_in[5];
  const float* Vw  = (const float*)d_in[6];
  const float* Vb  = (const float*)d_in[7];
  const float* A1  = (const float*)d_in[8];
  const float* a1  = (const float*)d_in[9];
  const float* A2  = (const float*)d_in[10];
  const float* a2  = (const float*)d_in[11];
  const float* D10 = (const float*)d_in[12];
  const float* e10 = (const float*)d_in[13];
  const float* D20 = (const float*)d_in[14];
  const float* e20 = (const float*)d_in[15];
  const float* D11 = (const float*)d_in[16];
  const float* e11 = (const float*)d_in[17];
  const float* D21 = (const float*)d_in[18];
  const float* e21 = (const float*)d_in[19];

  char* ws = (char*)d_ws;
  u16*  UVWt = (u16*)(ws);                  // 393216 B
  u16*  A1t  = (u16*)(ws + 393216);         // 65536 B
  u16*  A2t  = (u16*)(ws + 458752);         // 262144 B
  u16*  D10t = (u16*)(ws + 720896);         // 131072 B
  u16*  D20t = (u16*)(ws + 851968);         // 32768 B
  u16*  D11t = (u16*)(ws + 884736);         // 131072 B
  u16*  D21t = (u16*)(ws + 1015808);        // 32768 B
  float* bias = (float*)(ws + 1048576);     // 2688 f32

  auto nb = [](int n){ return dim3((unsigned)((n + 255)/256)); };
  pack_w<<<nb(65536),  256, 0, stream>>>(Ww,  UVWt, 128, 512,  0, 12);
  pack_w<<<nb(65536),  256, 0, stream>>>(Uw,  UVWt, 128, 512,  4, 12);
  pack_w<<<nb(65536),  256, 0, stream>>>(Vw,  UVWt, 128, 512,  8, 12);
  pack_w<<<nb(32768),  256, 0, stream>>>(A1,  A1t,  256, 128,  0, 8);
  pack_w<<<nb(131072), 256, 0, stream>>>(A2,  A2t,  128, 1024, 0, 4);
  pack_w<<<nb(65536),  256, 0, stream>>>(D10, D10t, 512, 128,  0, 16);
  pack_w<<<nb(16384),  256, 0, stream>>>(D20, D20t, 128, 128,  0, 4);
  pack_w<<<nb(65536),  256, 0, stream>>>(D11, D11t, 512, 128,  0, 16);
  pack_w<<<nb(16384),  256, 0, stream>>>(D21, D21t, 128, 128,  0, 4);
  pack_bias<<<nb(2688), 256, 0, stream>>>(Wb, Ub, Vb, a1, a2, e10, e20, e11, e21, bias);

  marn_mfma5<<<NBLK, 512, 0, stream>>>(eeg, eog, UVWt, A1t, A2t,
                                       D10t, D20t, D11t, D21t, bias, (float*)d_out);
}

// Round 14
// 7105.272 us; speedup vs baseline: 1.9720x; 1.0002x over previous
//
#include <hip/hip_runtime.h>

typedef unsigned short u16;
typedef unsigned int   u32;
typedef __attribute__((ext_vector_type(8))) __bf16 bf16x8;
typedef __attribute__((ext_vector_type(4))) float  f32x4;

#define T_STEPS 256
#define BATCH   512
#define RB      16
#define NBLK    32

__device__ __forceinline__ float b2f(u16 u){
  union { u32 i; float f; } v; v.i = ((u32)u) << 16; return v.f;
}
__device__ __forceinline__ u16 f2b(float f){
  u32 x = __float_as_uint(f);
  return (u16)((x + 0x7fffu + ((x >> 16) & 1u)) >> 16);
}
__device__ __forceinline__ float sigm_f(float x){ return 1.f/(1.f + __expf(-x)); }
__device__ __forceinline__ float tanh_f(float x){
  x = fminf(15.f, fmaxf(-15.f, x));
  float e = __expf(2.f*x);
  return (e - 1.f)/(e + 1.f);
}
__device__ __forceinline__ f32x4 MF(bf16x8 a, bf16x8 b, f32x4 c){
  return __builtin_amdgcn_mfma_f32_16x16x32_bf16(a, b, c, 0, 0, 0);
}
// Raw barrier: drain MY LDS ops (visibility), sync, but let global loads
// (vmcnt) stay in flight across the barrier (unlike __syncthreads).
__device__ __forceinline__ void BAR(){
  asm volatile("s_waitcnt lgkmcnt(0)" ::: "memory");
  __builtin_amdgcn_s_barrier();
}

// MFMA 16x16x32 bf16 lane maps (HW-verified m89):
//   A: row=lane&15, k=(lane>>4)*8+j ; B: col=lane&15 ; D: col=lane&15, row=(lane>>4)*4+reg
__device__ __forceinline__ bf16x8 frA(const u16* buf, int l, int kc, int RS){
  int r = l & 15;
  int byte = r*RS + kc*64 + ((l >> 4) << 4);
  byte ^= (r & 7) << 4;
  return *(const bf16x8*)((const char*)buf + byte);
}
__device__ __forceinline__ void st16(u16* buf, int r, int c, u16 v, int RS){
  int byte = r*RS + c*2; byte ^= (r & 7) << 4;
  *(u16*)((char*)buf + byte) = v;
}
__device__ __forceinline__ float ld16f(const u16* buf, int r, int c, int RS){
  int byte = r*RS + c*2; byte ^= (r & 7) << 4;
  return b2f(*(const u16*)((const char*)buf + byte));
}
__device__ __forceinline__ void st16x4(u16* buf, int r, int c, ushort4 v, int RS){
  int byte = r*RS + c*2; byte ^= (r & 7) << 4;
  *(ushort4*)((char*)buf + byte) = v;
}
// fragment-packed weights: [nt][kt][lane][8] bf16, one 16B load/lane
__device__ __forceinline__ bf16x8 frB(const u16* pk, int nt, int kt, int KT, int l){
  return *(const bf16x8*)(pk + ((((nt*KT + kt) << 6) + l) << 3));
}

// f32 src -> bf16 fragment-packed dst (verified round 9)
__global__ void pack_w(const float* __restrict__ src, u16* __restrict__ dst,
                       int Ksrc, int N, int ktOff, int KT)
{
  int i = blockIdx.x*256 + threadIdx.x;
  if (i >= Ksrc*N) return;
  int j = i & 7, l = (i >> 3) & 63, p = i >> 9;
  int nkt = Ksrc >> 5;
  int kt = p % nkt, nt = p / nkt;
  int k = (kt << 5) + ((l >> 4) << 3) + j;
  int n = (nt << 4) + (l & 15);
  dst[(((nt*KT + ktOff + kt) << 6) + l)*8 + j] = f2b(src[(size_t)k*N + n]);
}

__global__ void pack_bias(const float* Wb, const float* Ub, const float* Vb,
                          const float* a1, const float* a2,
                          const float* e10, const float* e20,
                          const float* e11, const float* e21, float* bout)
{
  int i = blockIdx.x*256 + threadIdx.x;
  if (i >= 2688) return;
  float v;
  if      (i < 512)  v = Wb[i];
  else if (i < 1024) { int n = i - 512; v = Wb[n] + Ub[n] + Vb[n]; }
  else if (i < 1152) v = a1[i - 1024];
  else if (i < 2176) v = a2[i - 1152];
  else if (i < 2304) v = e10[i - 2176];
  else if (i < 2432) v = e20[i - 2304];
  else if (i < 2560) v = e11[i - 2432];
  else               v = e21[i - 2560];
  bout[i] = v;
}

// 32 blocks x 512 threads (8 waves, 256-VGPR budget); block owns rows [b*16, b*16+16).
__global__ __launch_bounds__(512, 2) void marn_mfma6(
  const float* __restrict__ eeg, const float* __restrict__ eog,
  const u16* __restrict__ UVWt, const u16* __restrict__ A1t,
  const u16* __restrict__ A2t,  const u16* __restrict__ D10t,
  const u16* __restrict__ D20t, const u16* __restrict__ D11t,
  const u16* __restrict__ D21t, const float* __restrict__ bias,
  float* __restrict__ out)
{
  __shared__ u16  aS1[2][16*384];   // [x|h|z] per mod, RS=768   (24.0 KB)
  __shared__ u16  aS2a[16*256];     // [h0|h1], RS=512           ( 8.0 KB)
  __shared__ u16  aS2b[16*128];     // y, RS=256                 ( 4.0 KB)
  __shared__ u16  aS3a[2][16*512];  // att per mod, RS=1024      (32.0 KB)
  __shared__ u16  aS3b[2][16*128];  // u per mod, RS=256         ( 8.0 KB)
  __shared__ float bsh[2688];       //                           (10.5 KB)

  const int tid = threadIdx.x;
  const int w = tid >> 6, l = tid & 63;     // w in [0,8)
  const int hi = l >> 4, li = l & 15;
  const int r0 = blockIdx.x * RB;

  for (int i = tid; i < 2688; i += 512) bsh[i] = bias[i];
  for (int i = tid; i < 2*16*384; i += 512) ((u16*)aS1)[i] = 0;  // h,z zero at t=0
  float cst[2][4] = {{0,0,0,0},{0,0,0,0}};

  // x(0) prefetch: 8 u16 per thread (2 float4)
  const int xi = tid << 3;
  const int xm = xi >> 11, xrr = (xi >> 7) & 15, xc = xi & 127;
  const float* xsrc = (xm ? eog : eeg) + ((size_t)(r0 + xrr))*128 + xc;
  f32x4 xa = __builtin_nontemporal_load((const f32x4*)xsrc);
  f32x4 xb = __builtin_nontemporal_load((const f32x4*)(xsrc + 4));
  __syncthreads();                 // init visible before x-stage (R11 race fix)
  {
    ushort4 va, vb;
    va.x = f2b(xa[0]); va.y = f2b(xa[1]); va.z = f2b(xa[2]); va.w = f2b(xa[3]);
    vb.x = f2b(xb[0]); vb.y = f2b(xb[1]); vb.z = f2b(xb[2]); vb.w = f2b(xb[3]);
    st16x4(&aS1[xm][0], xrr, xc,     va, 768);
    st16x4(&aS1[xm][0], xrr, xc + 4, vb, 768);
  }
  __syncthreads();                 // x(0) staged

  for (int t = 0; t < T_STEPS; ++t){
    // ================= S1: gates GEMM, 3-kc double-buffered batches ========
    f32x4 ac0[4] = {{0,0,0,0},{0,0,0,0},{0,0,0,0},{0,0,0,0}};
    f32x4 ac1[4] = {{0,0,0,0},{0,0,0,0},{0,0,0,0},{0,0,0,0}};
    {
      bf16x8 wb0[12], wb1[12];
      #pragma unroll
      for (int j = 0; j < 3; ++j)
        #pragma unroll
        for (int g = 0; g < 4; ++g)
          wb0[j*4+g] = frB(UVWt, w + 8*g, j, 12, l);
      #pragma unroll
      for (int blk = 0; blk < 4; ++blk){
        bf16x8* cur = (blk & 1) ? wb1 : wb0;
        bf16x8* nxt = (blk & 1) ? wb0 : wb1;
        if (blk < 3){
          #pragma unroll
          for (int j = 0; j < 3; ++j)
            #pragma unroll
            for (int g = 0; g < 4; ++g)
              nxt[j*4+g] = frB(UVWt, w + 8*g, 3*blk + 3 + j, 12, l);
        }
        #pragma unroll
        for (int j = 0; j < 3; ++j){
          const int kc = 3*blk + j;
          bf16x8 fa0 = frA(&aS1[0][0], l, kc, 768);
          bf16x8 fa1 = frA(&aS1[1][0], l, kc, 768);
          #pragma unroll
          for (int g = 0; g < 4; ++g){
            ac0[g] = MF(fa0, cur[j*4+g], ac0[g]);
            ac1[g] = MF(fa1, cur[j*4+g], ac1[g]);
          }
        }
      }
    }
    // prefetch S2a B-frags (ride across B1/B2)
    bf16x8 wa1[8];
    #pragma unroll
    for (int kc = 0; kc < 8; ++kc) wa1[kc] = frB(A1t, w, kc, 8, l);
    BAR();                                         // B1: S1 LDS reads done

    // ---- S1ep: in-register LSTHM cell update ----
    {
      const float* bg = bsh + (t == 0 ? 0 : 512);
      const int col = w*16 + li;
      #pragma unroll
      for (int jr = 0; jr < 4; ++jr){
        const int row = hi*4 + jr;
        {
          float f  = sigm_f(ac0[0][jr] + bg[col]);
          float ii = sigm_f(ac0[1][jr] + bg[128+col]);
          float o  = sigm_f(ac0[2][jr] + bg[256+col]);
          float ch = tanh_f(ac0[3][jr] + bg[384+col]);
          cst[0][jr] = f*cst[0][jr] + ii*ch;
          u16 hb = f2b(tanh_f(cst[0][jr])*o);
          st16(&aS1[0][0], row, 128 + col, hb, 768);
          st16(aS2a, row, col, hb, 512);
        }
        {
          float f  = sigm_f(ac1[0][jr] + bg[col]);
          float ii = sigm_f(ac1[1][jr] + bg[128+col]);
          float o  = sigm_f(ac1[2][jr] + bg[256+col]);
          float ch = tanh_f(ac1[3][jr] + bg[384+col]);
          cst[1][jr] = f*cst[1][jr] + ii*ch;
          u16 hb = f2b(tanh_f(cst[1][jr])*o);
          st16(&aS1[1][0], row, 128 + col, hb, 768);
          st16(aS2a, row, 128 + col, hb, 512);
        }
      }
    }
    // prefetch first half of S2b B-frags (rides across B2/B3)
    bf16x8 wa2A[16];
    #pragma unroll
    for (int s = 0; s < 4; ++s)
      #pragma unroll
      for (int kc = 0; kc < 4; ++kc)
        wa2A[s*4+kc] = frB(A2t, w + 16*s, kc, 4, l);
    BAR();                                         // B2: h visible

    // ---- S2a: y = tanh([h0|h1]@A1 + a1)  (prefetched B) ----
    {
      f32x4 acc = {0,0,0,0};
      #pragma unroll
      for (int kc = 0; kc < 8; ++kc)
        acc = MF(frA(aS2a, l, kc, 512), wa1[kc], acc);
      const int col = w*16 + li;
      #pragma unroll
      for (int jr = 0; jr < 4; ++jr)
        st16(aS2b, hi*4 + jr, col, f2b(tanh_f(acc[jr] + bsh[1024 + col])), 256);
    }
    // second half of S2b B-frags + x(t+1) (ride across B3)
    bf16x8 wa2B[16];
    #pragma unroll
    for (int s = 0; s < 4; ++s)
      #pragma unroll
      for (int kc = 0; kc < 4; ++kc)
        wa2B[s*4+kc] = frB(A2t, w + 8 + 16*s, kc, 4, l);
    {
      int tn = (t + 1 < T_STEPS) ? t + 1 : t;
      xa = __builtin_nontemporal_load((const f32x4*)(xsrc + (size_t)tn*BATCH*128));
      xb = __builtin_nontemporal_load((const f32x4*)(xsrc + (size_t)tn*BATCH*128 + 4));
    }
    BAR();                                         // B3: y visible

    // ---- S2b + SM: logits (g-blocks w, w+8), 4-way softmax, att ----
    {
      bf16x8 yf[4];
      #pragma unroll
      for (int kc = 0; kc < 4; ++kc) yf[kc] = frA(aS2b, l, kc, 256);
      const float* a2f = bsh + 1152;
      f32x4 qq[8];
      #pragma unroll
      for (int s = 0; s < 8; ++s) qq[s] = (f32x4){0,0,0,0};
      #pragma unroll
      for (int s = 0; s < 4; ++s)
        #pragma unroll
        for (int kc = 0; kc < 4; ++kc){
          qq[s]     = MF(yf[kc], wa2A[s*4+kc], qq[s]);
          qq[4 + s] = MF(yf[kc], wa2B[s*4+kc], qq[4 + s]);
        }
      #pragma unroll
      for (int gq = 0; gq < 2; ++gq){
        const int gb = w + 8*gq;
        const int g = gb*16 + li;
        #pragma unroll
        for (int jr = 0; jr < 4; ++jr){
          const int row = hi*4 + jr;
          float v0 = qq[4*gq + 0][jr] + a2f[g];
          float v1 = qq[4*gq + 1][jr] + a2f[256 + g];
          float v2 = qq[4*gq + 2][jr] + a2f[512 + g];
          float v3 = qq[4*gq + 3][jr] + a2f[768 + g];
          float mx = fmaxf(fmaxf(v0,v1), fmaxf(v2,v3));
          float e0 = __expf(v0-mx), e1 = __expf(v1-mx);
          float e2 = __expf(v2-mx), e3 = __expf(v3-mx);
          float inv = 1.f/(e0+e1+e2+e3);
          float h0v = ld16f(aS2a, row, g & 127, 512);
          float h1v = ld16f(aS2a, row, 128 + (g & 127), 512);
          st16(&aS3a[0][0], row, g,       f2b(e0*inv*h0v), 1024);
          st16(&aS3a[0][0], row, 256 + g, f2b(e1*inv*h0v), 1024);
          st16(&aS3a[1][0], row, g,       f2b(e2*inv*h1v), 1024);
          st16(&aS3a[1][0], row, 256 + g, f2b(e3*inv*h1v), 1024);
        }
      }
    }
    // prefetch S3a m=0 B-frags (ride across B4)
    bf16x8 wd0[16];
    #pragma unroll
    for (int kc = 0; kc < 16; ++kc) wd0[kc] = frB(D10t, w, kc, 16, l);
    BAR();                                         // B4: att visible

    // ---- S3a: u = tanh(att@D1 + e1)  (col-block w, both mods) ----
    {
      bf16x8 wd1[16];
      #pragma unroll
      for (int kc = 0; kc < 16; ++kc) wd1[kc] = frB(D11t, w, kc, 16, l);
      const int col = w*16 + li;
      {
        f32x4 acc = {0,0,0,0};
        #pragma unroll
        for (int kc = 0; kc < 16; ++kc)
          acc = MF(frA(&aS3a[0][0], l, kc, 1024), wd0[kc], acc);
        const float* e1f = bsh + 2176;
        #pragma unroll
        for (int jr = 0; jr < 4; ++jr)
          st16(&aS3b[0][0], hi*4 + jr, col, f2b(tanh_f(acc[jr] + e1f[col])), 256);
      }
      {
        f32x4 acc = {0,0,0,0};
        #pragma unroll
        for (int kc = 0; kc < 16; ++kc)
          acc = MF(frA(&aS3a[1][0], l, kc, 1024), wd1[kc], acc);
        const float* e1f = bsh + 2432;
        #pragma unroll
        for (int jr = 0; jr < 4; ++jr)
          st16(&aS3b[1][0], hi*4 + jr, col, f2b(tanh_f(acc[jr] + e1f[col])), 256);
      }
    }
    // prefetch S3b B-frags (ride across B5)
    bf16x8 wd2m0[4], wd2m1[4];
    #pragma unroll
    for (int kc = 0; kc < 4; ++kc){
      wd2m0[kc] = frB(D20t, w, kc, 4, l);
      wd2m1[kc] = frB(D21t, w, kc, 4, l);
    }
    BAR();                                         // B5: u visible

    // ---- S3b: z = u@D2 + e2 ; NT-store out ; z + x(t+1) into aS1 ----
    {
      const int col = w*16 + li;
      {
        f32x4 acc = {0,0,0,0};
        #pragma unroll
        for (int kc = 0; kc < 4; ++kc)
          acc = MF(frA(&aS3b[0][0], l, kc, 256), wd2m0[kc], acc);
        const float* e2f = bsh + 2304;
        #pragma unroll
        for (int jr = 0; jr < 4; ++jr){
          const int row = hi*4 + jr;
          float z = acc[jr] + e2f[col];
          __builtin_nontemporal_store(z, &out[((size_t)t*BATCH + r0 + row)*256 + col]);
          st16(&aS1[0][0], row, 256 + col, f2b(z), 768);
        }
      }
      {
        f32x4 acc = {0,0,0,0};
        #pragma unroll
        for (int kc = 0; kc < 4; ++kc)
          acc = MF(frA(&aS3b[1][0], l, kc, 256), wd2m1[kc], acc);
        const float* e2f = bsh + 2560;
        #pragma unroll
        for (int jr = 0; jr < 4; ++jr){
          const int row = hi*4 + jr;
          float z = acc[jr] + e2f[col];
          __builtin_nontemporal_store(z, &out[((size_t)t*BATCH + r0 + row)*256 + 128 + col]);
          st16(&aS1[1][0], row, 256 + col, f2b(z), 768);
        }
      }
    }
    {
      ushort4 va, vb;
      va.x = f2b(xa[0]); va.y = f2b(xa[1]); va.z = f2b(xa[2]); va.w = f2b(xa[3]);
      vb.x = f2b(xb[0]); vb.y = f2b(xb[1]); vb.z = f2b(xb[2]); vb.w = f2b(xb[3]);
      st16x4(&aS1[xm][0], xrr, xc,     va, 768);
      st16x4(&aS1[xm][0], xrr, xc + 4, vb, 768);
    }
    BAR();                                         // B6: z,x visible for next S1
  }
}

extern "C" void kernel_launch(void* const* d_in, const int* in_sizes, int n_in,
                              void* d_out, int out_size, void* d_ws, size_t ws_size,
                              hipStream_t stream)
{
  const float* eeg = (const float*)d_in[0];
  const float* eog = (const float*)d_in[1];
  const float* Ww  = (const float*)d_in[2];
  const float* Wb  = (const float*)d_in[3];
  const float* Uw  = (const float*)d_in[4];
  const float* Ub  = (const float*)d_in[5];
  const float* Vw  = (const float*)d_in[6];
  const float* Vb  = (const float*)d_in[7];
  const float* A1  = (const float*)d_in[8];
  const float* a1  = (const float*)d_in[9];
  const float* A2  = (const float*)d_in[10];
  const float* a2  = (const float*)d_in[11];
  const float* D10 = (const float*)d_in[12];
  const float* e10 = (const float*)d_in[13];
  const float* D20 = (const float*)d_in[14];
  const float* e20 = (const float*)d_in[15];
  const float* D11 = (const float*)d_in[16];
  const float* e11 = (const float*)d_in[17];
  const float* D21 = (const float*)d_in[18];
  const float* e21 = (const float*)d_in[19];

  char* ws = (char*)d_ws;
  u16*  UVWt = (u16*)(ws);                  // 393216 B
  u16*  A1t  = (u16*)(ws + 393216);         // 65536 B
  u16*  A2t  = (u16*)(ws + 458752);         // 262144 B
  u16*  D10t = (u16*)(ws + 720896);         // 131072 B
  u16*  D20t = (u16*)(ws + 851968);         // 32768 B
  u16*  D11t = (u16*)(ws + 884736);         // 131072 B
  u16*  D21t = (u16*)(ws + 1015808);        // 32768 B
  float* bias = (float*)(ws + 1048576);     // 2688 f32

  auto nb = [](int n){ return dim3((unsigned)((n + 255)/256)); };
  pack_w<<<nb(65536),  256, 0, stream>>>(Ww,  UVWt, 128, 512,  0, 12);
  pack_w<<<nb(65536),  256, 0, stream>>>(Uw,  UVWt, 128, 512,  4, 12);
  pack_w<<<nb(65536),  256, 0, stream>>>(Vw,  UVWt, 128, 512,  8, 12);
  pack_w<<<nb(32768),  256, 0, stream>>>(A1,  A1t,  256, 128,  0, 8);
  pack_w<<<nb(131072), 256, 0, stream>>>(A2,  A2t,  128, 1024, 0, 4);
  pack_w<<<nb(65536),  256, 0, stream>>>(D10, D10t, 512, 128,  0, 16);
  pack_w<<<nb(16384),  256, 0, stream>>>(D20, D20t, 128, 128,  0, 4);
  pack_w<<<nb(65536),  256, 0, stream>>>(D11, D11t, 512, 128,  0, 16);
  pack_w<<<nb(16384),  256, 0, stream>>>(D21, D21t, 128, 128,  0, 4);
  pack_bias<<<nb(2688), 256, 0, stream>>>(Wb, Ub, Vb, a1, a2, e10, e20, e11, e21, bias);

  marn_mfma6<<<NBLK, 512, 0, stream>>>(eeg, eog, UVWt, A1t, A2t,
                                       D10t, D20t, D11t, D21t, bias, (float*)d_out);
}

// Round 15
// 6608.057 us; speedup vs baseline: 2.1204x; 1.0752x over previous
//
#include <hip/hip_runtime.h>

typedef unsigned short u16;
typedef unsigned int   u32;
typedef __attribute__((ext_vector_type(8))) __bf16 bf16x8;
typedef __attribute__((ext_vector_type(4))) float  f32x4;

#define T_STEPS 256
#define BATCH   512
#define RB      16
#define NBLK    32

#define WAITV(N) asm volatile("s_waitcnt vmcnt(" #N ")" ::: "memory")
#define LGKM0    asm volatile("s_waitcnt lgkmcnt(0)" ::: "memory")

__device__ __forceinline__ float b2f(u16 u){
  union { u32 i; float f; } v; v.i = ((u32)u) << 16; return v.f;
}
__device__ __forceinline__ u16 f2b(float f){
  u32 x = __float_as_uint(f);
  return (u16)((x + 0x7fffu + ((x >> 16) & 1u)) >> 16);
}
__device__ __forceinline__ float sigm_f(float x){ return 1.f/(1.f + __expf(-x)); }
__device__ __forceinline__ float tanh_f(float x){
  x = fminf(15.f, fmaxf(-15.f, x));
  float e = __expf(2.f*x);
  return (e - 1.f)/(e + 1.f);
}
__device__ __forceinline__ f32x4 MF(bf16x8 a, bf16x8 b, f32x4 c){
  return __builtin_amdgcn_mfma_f32_16x16x32_bf16(a, b, c, 0, 0, 0);
}
// lgkm-only barrier: LDS visibility, but vmem (DMA) stays in flight across it
__device__ __forceinline__ void BAR(){
  asm volatile("s_waitcnt lgkmcnt(0)" ::: "memory");
  __builtin_amdgcn_s_barrier();
}

// async global->LDS DMA, 16B per lane; LDS dest = uniform base + lane*16
__device__ __forceinline__ void dma16(const u16* g, u16* l){
  __builtin_amdgcn_global_load_lds(
      (const __attribute__((address_space(1))) void*)g,
      (__attribute__((address_space(3))) void*)l, 16, 0, 0);
}
// one weight group = 4 fragments of 1KB into ring half `par`
__device__ __forceinline__ void issueG(const u16* f0, const u16* f1,
                                       const u16* f2, const u16* f3,
                                       u16* ringW, int par, int l){
  u16* s = ringW + par*2048;
  dma16(f0 + l*8, s);
  dma16(f1 + l*8, s + 512);
  dma16(f2 + l*8, s + 1024);
  dma16(f3 + l*8, s + 1536);
}
__device__ __forceinline__ const u16* fp(const u16* pk, int nt, int kt, int KT){
  return pk + (size_t)(nt*KT + kt)*512;
}
__device__ __forceinline__ bf16x8 rdW(const u16* ringW, int par, int j, int l){
  return *(const bf16x8*)(ringW + par*2048 + j*512 + l*8);
}

// MFMA 16x16x32 bf16 lane maps (HW-verified m89)
__device__ __forceinline__ bf16x8 frA(const u16* buf, int l, int kc, int RS){
  int r = l & 15;
  int byte = r*RS + kc*64 + ((l >> 4) << 4);
  byte ^= (r & 7) << 4;
  return *(const bf16x8*)((const char*)buf + byte);
}
__device__ __forceinline__ void st16(u16* buf, int r, int c, u16 v, int RS){
  int byte = r*RS + c*2; byte ^= (r & 7) << 4;
  *(u16*)((char*)buf + byte) = v;
}
__device__ __forceinline__ float ld16f(const u16* buf, int r, int c, int RS){
  int byte = r*RS + c*2; byte ^= (r & 7) << 4;
  return b2f(*(const u16*)((const char*)buf + byte));
}
__device__ __forceinline__ void st16x4(u16* buf, int r, int c, ushort4 v, int RS){
  int byte = r*RS + c*2; byte ^= (r & 7) << 4;
  *(ushort4*)((char*)buf + byte) = v;
}

// f32 src -> bf16 fragment-packed dst (verified round 9)
__global__ void pack_w(const float* __restrict__ src, u16* __restrict__ dst,
                       int Ksrc, int N, int ktOff, int KT)
{
  int i = blockIdx.x*256 + threadIdx.x;
  if (i >= Ksrc*N) return;
  int j = i & 7, l = (i >> 3) & 63, p = i >> 9;
  int nkt = Ksrc >> 5;
  int kt = p % nkt, nt = p / nkt;
  int k = (kt << 5) + ((l >> 4) << 3) + j;
  int n = (nt << 4) + (l & 15);
  dst[(((nt*KT + ktOff + kt) << 6) + l)*8 + j] = f2b(src[(size_t)k*N + n]);
}

__global__ void pack_bias(const float* Wb, const float* Ub, const float* Vb,
                          const float* a1, const float* a2,
                          const float* e10, const float* e20,
                          const float* e11, const float* e21, float* bout)
{
  int i = blockIdx.x*256 + threadIdx.x;
  if (i >= 2688) return;
  float v;
  if      (i < 512)  v = Wb[i];
  else if (i < 1024) { int n = i - 512; v = Wb[n] + Ub[n] + Vb[n]; }
  else if (i < 1152) v = a1[i - 1024];
  else if (i < 2176) v = a2[i - 1152];
  else if (i < 2304) v = e10[i - 2176];
  else if (i < 2432) v = e20[i - 2304];
  else if (i < 2560) v = e11[i - 2432];
  else               v = e21[i - 2560];
  bout[i] = v;
}

// 32 blocks x 512 threads (8 waves). Per-wave DMA weight stream through a
// private 8KB LDS ring; counted vmcnt; weights ride across all barriers.
__global__ __launch_bounds__(512, 2) void marn_dma(
  const float* __restrict__ eeg, const float* __restrict__ eog,
  const u16* __restrict__ UVWt, const u16* __restrict__ A1t,
  const u16* __restrict__ A2t,  const u16* __restrict__ D10t,
  const u16* __restrict__ D20t, const u16* __restrict__ D11t,
  const u16* __restrict__ D21t, const float* __restrict__ bias,
  float* __restrict__ out)
{
  __shared__ u16 aS1[2][16*384];   // [x|h|z] per mod, RS=768   (24 KB)
  __shared__ u16 aS2a[16*256];     // [h0|h1], RS=512           ( 8 KB)
  __shared__ u16 aS2b[16*128];     // y, RS=256                 ( 4 KB)
  __shared__ u16 aS3a[2][16*512];  // att per mod, RS=1024      (32 KB)
  __shared__ u16 aS3b[2][16*128];  // u per mod, RS=256         ( 8 KB)
  __shared__ u16 ring[8][4096];    // per-wave weight rings     (64 KB)

  const int tid = threadIdx.x;
  const int w = tid >> 6, l = tid & 63;     // 8 waves
  const int hi = l >> 4, li = l & 15;
  const int r0 = blockIdx.x * RB;
  u16* ringW = &ring[w][0];

  for (int i = tid; i < 2*16*384; i += 512) ((u16*)aS1)[i] = 0;  // h,z zero
  float cst[2][4] = {{0,0,0,0},{0,0,0,0}};

  // per-thread bias registers (replaces LDS bias table)
  const int col = w*16 + li;
  const int g1c = (w + 8)*16 + li;
  float bW[4], bA[4], a2b0[4], a2b1[4];
  #pragma unroll
  for (int q = 0; q < 4; ++q){
    bW[q]   = bias[q*128 + col];
    bA[q]   = bias[512 + q*128 + col];
    a2b0[q] = bias[1152 + q*256 + col];
    a2b1[q] = bias[1152 + q*256 + g1c];
  }
  const float a1b  = bias[1024 + col];
  const float e1b0 = bias[2176 + col], e1b1 = bias[2432 + col];
  const float e2b0 = bias[2304 + col], e2b1 = bias[2560 + col];

  // x(0) prefetch: 8 u16 per thread (2 float4)
  const int xi = tid << 3;
  const int xm = xi >> 11, xrr = (xi >> 7) & 15, xc = xi & 127;
  const float* xsrc = (xm ? eog : eeg) + ((size_t)(r0 + xrr))*128 + xc;
  f32x4 xa = __builtin_nontemporal_load((const f32x4*)xsrc);
  f32x4 xb = __builtin_nontemporal_load((const f32x4*)(xsrc + 4));
  __syncthreads();                 // init visible before x-stage
  {
    ushort4 va, vb;
    va.x = f2b(xa[0]); va.y = f2b(xa[1]); va.z = f2b(xa[2]); va.w = f2b(xa[3]);
    vb.x = f2b(xb[0]); vb.y = f2b(xb[1]); vb.z = f2b(xb[2]); vb.w = f2b(xb[3]);
    st16x4(&aS1[xm][0], xrr, xc,     va, 768);
    st16x4(&aS1[xm][0], xrr, xc + 4, vb, 768);
  }
  __syncthreads();                 // x(0) staged

  // DMA prologue: groups 0,1 (S1 kc=0,1)
  issueG(fp(UVWt,w,0,12), fp(UVWt,w+8,0,12), fp(UVWt,w+16,0,12), fp(UVWt,w+24,0,12), ringW, 0, l);
  issueG(fp(UVWt,w,1,12), fp(UVWt,w+8,1,12), fp(UVWt,w+16,1,12), fp(UVWt,w+24,1,12), ringW, 1, l);

  for (int t = 0; t < T_STEPS; ++t){
    // ===== S1: gates GEMM, consume groups 0..11 =====
    f32x4 ac0[4] = {{0,0,0,0},{0,0,0,0},{0,0,0,0},{0,0,0,0}};
    f32x4 ac1[4] = {{0,0,0,0},{0,0,0,0},{0,0,0,0},{0,0,0,0}};
    #pragma unroll
    for (int kc = 0; kc < 12; ++kc){
      WAITV(4);
      bf16x8 b0 = rdW(ringW, kc&1, 0, l);
      bf16x8 b1 = rdW(ringW, kc&1, 1, l);
      bf16x8 b2 = rdW(ringW, kc&1, 2, l);
      bf16x8 b3 = rdW(ringW, kc&1, 3, l);
      bf16x8 fa0 = frA(&aS1[0][0], l, kc, 768);
      bf16x8 fa1 = frA(&aS1[1][0], l, kc, 768);
      ac0[0] = MF(fa0, b0, ac0[0]);  ac1[0] = MF(fa1, b0, ac1[0]);
      ac0[1] = MF(fa0, b1, ac0[1]);  ac1[1] = MF(fa1, b1, ac1[1]);
      ac0[2] = MF(fa0, b2, ac0[2]);  ac1[2] = MF(fa1, b2, ac1[2]);
      ac0[3] = MF(fa0, b3, ac0[3]);  ac1[3] = MF(fa1, b3, ac1[3]);
      LGKM0;
      if (kc < 10){
        const int k2 = kc + 2;
        issueG(fp(UVWt,w,k2,12), fp(UVWt,w+8,k2,12), fp(UVWt,w+16,k2,12), fp(UVWt,w+24,k2,12), ringW, k2&1, l);
      } else if (kc == 10){
        issueG(fp(A1t,w,0,8), fp(A1t,w,1,8), fp(A1t,w,2,8), fp(A1t,w,3,8), ringW, 0, l);
      } else {
        issueG(fp(A1t,w,4,8), fp(A1t,w,5,8), fp(A1t,w,6,8), fp(A1t,w,7,8), ringW, 1, l);
      }
    }
    BAR();                                        // B1

    // ---- S1ep: in-register LSTHM cell update ----
    {
      #pragma unroll
      for (int jr = 0; jr < 4; ++jr){
        const int row = hi*4 + jr;
        {
          float f  = sigm_f(ac0[0][jr] + (t==0 ? bW[0] : bA[0]));
          float ii = sigm_f(ac0[1][jr] + (t==0 ? bW[1] : bA[1]));
          float o  = sigm_f(ac0[2][jr] + (t==0 ? bW[2] : bA[2]));
          float ch = tanh_f(ac0[3][jr] + (t==0 ? bW[3] : bA[3]));
          cst[0][jr] = f*cst[0][jr] + ii*ch;
          u16 hb = f2b(tanh_f(cst[0][jr])*o);
          st16(&aS1[0][0], row, 128 + col, hb, 768);
          st16(aS2a, row, col, hb, 512);
        }
        {
          float f  = sigm_f(ac1[0][jr] + (t==0 ? bW[0] : bA[0]));
          float ii = sigm_f(ac1[1][jr] + (t==0 ? bW[1] : bA[1]));
          float o  = sigm_f(ac1[2][jr] + (t==0 ? bW[2] : bA[2]));
          float ch = tanh_f(ac1[3][jr] + (t==0 ? bW[3] : bA[3]));
          cst[1][jr] = f*cst[1][jr] + ii*ch;
          u16 hb = f2b(tanh_f(cst[1][jr])*o);
          st16(&aS1[1][0], row, 128 + col, hb, 768);
          st16(aS2a, row, 128 + col, hb, 512);
        }
      }
    }
    BAR();                                        // B2

    // ===== S2a: consume groups 12,13 =====
    {
      f32x4 accA = {0,0,0,0};
      WAITV(4);
      #pragma unroll
      for (int j = 0; j < 4; ++j)
        accA = MF(frA(aS2a, l, j, 512), rdW(ringW, 0, j, l), accA);
      LGKM0;
      issueG(fp(A2t,w,0,4), fp(A2t,w,1,4), fp(A2t,w,2,4), fp(A2t,w,3,4), ringW, 0, l);
      WAITV(4);
      #pragma unroll
      for (int j = 0; j < 4; ++j)
        accA = MF(frA(aS2a, l, 4+j, 512), rdW(ringW, 1, j, l), accA);
      LGKM0;
      issueG(fp(A2t,w+16,0,4), fp(A2t,w+16,1,4), fp(A2t,w+16,2,4), fp(A2t,w+16,3,4), ringW, 1, l);
      #pragma unroll
      for (int jr = 0; jr < 4; ++jr)
        st16(aS2b, hi*4 + jr, col, f2b(tanh_f(accA[jr] + a1b)), 256);
    }
    BAR();                                        // B3

    // ===== S2b: consume groups 14..21; softmax; att =====
    {
      bf16x8 yf[4];
      #pragma unroll
      for (int kc = 0; kc < 4; ++kc) yf[kc] = frA(aS2b, l, kc, 256);
      f32x4 qq[8];
      #pragma unroll
      for (int s = 0; s < 8; ++s) qq[s] = (f32x4){0,0,0,0};
      #pragma unroll
      for (int j = 0; j < 8; ++j){
        WAITV(4);
        #pragma unroll
        for (int kc = 0; kc < 4; ++kc)
          qq[j] = MF(yf[kc], rdW(ringW, j&1, kc, l), qq[j]);
        LGKM0;
        if (j < 6){
          const int j2 = j + 2;
          const int nt = (j2 < 4) ? (w + 16*j2) : (w + 8 + 16*(j2 - 4));
          issueG(fp(A2t,nt,0,4), fp(A2t,nt,1,4), fp(A2t,nt,2,4), fp(A2t,nt,3,4), ringW, j2&1, l);
        } else if (j == 6){
          issueG(fp(D10t,w,0,16), fp(D10t,w,1,16), fp(D10t,w,2,16), fp(D10t,w,3,16), ringW, 0, l);
        } else {
          issueG(fp(D10t,w,4,16), fp(D10t,w,5,16), fp(D10t,w,6,16), fp(D10t,w,7,16), ringW, 1, l);
        }
      }
      #pragma unroll
      for (int gq = 0; gq < 2; ++gq){
        const int g = (w + 8*gq)*16 + li;
        const float* ab = gq ? a2b1 : a2b0;
        #pragma unroll
        for (int jr = 0; jr < 4; ++jr){
          const int row = hi*4 + jr;
          float v0 = qq[4*gq + 0][jr] + ab[0];
          float v1 = qq[4*gq + 1][jr] + ab[1];
          float v2 = qq[4*gq + 2][jr] + ab[2];
          float v3 = qq[4*gq + 3][jr] + ab[3];
          float mx = fmaxf(fmaxf(v0,v1), fmaxf(v2,v3));
          float e0 = __expf(v0-mx), e1 = __expf(v1-mx);
          float e2 = __expf(v2-mx), e3 = __expf(v3-mx);
          float inv = 1.f/(e0+e1+e2+e3);
          float h0v = ld16f(aS2a, row, g & 127, 512);
          float h1v = ld16f(aS2a, row, 128 + (g & 127), 512);
          st16(&aS3a[0][0], row, g,       f2b(e0*inv*h0v), 1024);
          st16(&aS3a[0][0], row, 256 + g, f2b(e1*inv*h0v), 1024);
          st16(&aS3a[1][0], row, g,       f2b(e2*inv*h1v), 1024);
          st16(&aS3a[1][0], row, 256 + g, f2b(e3*inv*h1v), 1024);
        }
      }
    }
    BAR();                                        // B4

    // ===== S3a: consume groups 22..29 =====
    {
      f32x4 au0 = {0,0,0,0}, au1 = {0,0,0,0};
      #pragma unroll
      for (int j = 0; j < 8; ++j){
        if (j < 2) { WAITV(4); } else { WAITV(6); }   // +2 for x loads in flight
        const u16* src = (j < 4) ? &aS3a[0][0] : &aS3a[1][0];
        #pragma unroll
        for (int i = 0; i < 4; ++i){
          bf16x8 a = frA(src, l, (j&3)*4 + i, 1024);
          bf16x8 b = rdW(ringW, j&1, i, l);
          if (j < 4) au0 = MF(a, b, au0); else au1 = MF(a, b, au1);
        }
        LGKM0;
        if (j < 6){
          const int j2 = j + 2;
          const u16* Dt = (j2 < 4) ? D10t : D11t;
          const int ktb = (j2 & 3)*4;
          issueG(fp(Dt,w,ktb,16), fp(Dt,w,ktb+1,16), fp(Dt,w,ktb+2,16), fp(Dt,w,ktb+3,16), ringW, j2&1, l);
        } else if (j == 6){
          issueG(fp(D20t,w,0,4), fp(D20t,w,1,4), fp(D20t,w,2,4), fp(D20t,w,3,4), ringW, 0, l);
        } else {
          issueG(fp(D21t,w,0,4), fp(D21t,w,1,4), fp(D21t,w,2,4), fp(D21t,w,3,4), ringW, 1, l);
        }
        if (j == 1){
          int tn = (t + 1 < T_STEPS) ? t + 1 : t;
          xa = __builtin_nontemporal_load((const f32x4*)(xsrc + (size_t)tn*BATCH*128));
          xb = __builtin_nontemporal_load((const f32x4*)(xsrc + (size_t)tn*BATCH*128 + 4));
        }
      }
      #pragma unroll
      for (int jr = 0; jr < 4; ++jr){
        st16(&aS3b[0][0], hi*4 + jr, col, f2b(tanh_f(au0[jr] + e1b0)), 256);
        st16(&aS3b[1][0], hi*4 + jr, col, f2b(tanh_f(au1[jr] + e1b1)), 256);
      }
    }
    BAR();                                        // B5

    // ===== S3b: consume groups 30,31; z; output =====
    {
      // mod0 (group 30, parity 0)
      WAITV(4);
      f32x4 az0 = {0,0,0,0};
      #pragma unroll
      for (int kc = 0; kc < 4; ++kc)
        az0 = MF(frA(&aS3b[0][0], l, kc, 256), rdW(ringW, 0, kc, l), az0);
      #pragma unroll
      for (int jr = 0; jr < 4; ++jr){
        const int row = hi*4 + jr;
        float z = az0[jr] + e2b0;
        __builtin_nontemporal_store(z, &out[((size_t)t*BATCH + r0 + row)*256 + col]);
        st16(&aS1[0][0], row, 256 + col, f2b(z), 768);
      }
      LGKM0;
      issueG(fp(UVWt,w,0,12), fp(UVWt,w+8,0,12), fp(UVWt,w+16,0,12), fp(UVWt,w+24,0,12), ringW, 0, l);
      // mod1 (group 31, parity 1)
      WAITV(8);
      f32x4 az1 = {0,0,0,0};
      #pragma unroll
      for (int kc = 0; kc < 4; ++kc)
        az1 = MF(frA(&aS3b[1][0], l, kc, 256), rdW(ringW, 1, kc, l), az1);
      #pragma unroll
      for (int jr = 0; jr < 4; ++jr){
        const int row = hi*4 + jr;
        float z = az1[jr] + e2b1;
        __builtin_nontemporal_store(z, &out[((size_t)t*BATCH + r0 + row)*256 + 128 + col]);
        st16(&aS1[1][0], row, 256 + col, f2b(z), 768);
      }
      LGKM0;
      issueG(fp(UVWt,w,1,12), fp(UVWt,w+8,1,12), fp(UVWt,w+16,1,12), fp(UVWt,w+24,1,12), ringW, 1, l);
    }
    // stage x(t+1)
    {
      ushort4 va, vb;
      va.x = f2b(xa[0]); va.y = f2b(xa[1]); va.z = f2b(xa[2]); va.w = f2b(xa[3]);
      vb.x = f2b(xb[0]); vb.y = f2b(xb[1]); vb.z = f2b(xb[2]); vb.w = f2b(xb[3]);
      st16x4(&aS1[xm][0], xrr, xc,     va, 768);
      st16x4(&aS1[xm][0], xrr, xc + 4, vb, 768);
    }
    BAR();                                        // B6
  }
}

extern "C" void kernel_launch(void* const* d_in, const int* in_sizes, int n_in,
                              void* d_out, int out_size, void* d_ws, size_t ws_size,
                              hipStream_t stream)
{
  const float* eeg = (const float*)d_in[0];
  const float* eog = (const float*)d_in[1];
  const float* Ww  = (const float*)d_in[2];
  const float* Wb  = (const float*)d_in[3];
  const float* Uw  = (const float*)d_in[4];
  const float* Ub  = (const float*)d_in[5];
  const float* Vw  = (const float*)d_in[6];
  const float* Vb  = (const float*)d_in[7];
  const float* A1  = (const float*)d_in[8];
  const float* a1  = (const float*)d_in[9];
  const float* A2  = (const float*)d_in[10];
  const float* a2  = (const float*)d_in[11];
  const float* D10 = (const float*)d_in[12];
  const float* e10 = (const float*)d_in[13];
  const float* D20 = (const float*)d_in[14];
  const float* e20 = (const float*)d_in[15];
  const float* D11 = (const float*)d_in[16];
  const float* e11 = (const float*)d_in[17];
  const float* D21 = (const float*)d_in[18];
  const float* e21 = (const float*)d_in[19];

  char* ws = (char*)d_ws;
  u16*  UVWt = (u16*)(ws);                  // 393216 B
  u16*  A1t  = (u16*)(ws + 393216);         // 65536 B
  u16*  A2t  = (u16*)(ws + 458752);         // 262144 B
  u16*  D10t = (u16*)(ws + 720896);         // 131072 B
  u16*  D20t = (u16*)(ws + 851968);         // 32768 B
  u16*  D11t = (u16*)(ws + 884736);         // 131072 B
  u16*  D21t = (u16*)(ws + 1015808);        // 32768 B
  float* bias = (float*)(ws + 1048576);     // 2688 f32

  auto nb = [](int n){ return dim3((unsigned)((n + 255)/256)); };
  pack_w<<<nb(65536),  256, 0, stream>>>(Ww,  UVWt, 128, 512,  0, 12);
  pack_w<<<nb(65536),  256, 0, stream>>>(Uw,  UVWt, 128, 512,  4, 12);
  pack_w<<<nb(65536),  256, 0, stream>>>(Vw,  UVWt, 128, 512,  8, 12);
  pack_w<<<nb(32768),  256, 0, stream>>>(A1,  A1t,  256, 128,  0, 8);
  pack_w<<<nb(131072), 256, 0, stream>>>(A2,  A2t,  128, 1024, 0, 4);
  pack_w<<<nb(65536),  256, 0, stream>>>(D10, D10t, 512, 128,  0, 16);
  pack_w<<<nb(16384),  256, 0, stream>>>(D20, D20t, 128, 128,  0, 4);
  pack_w<<<nb(65536),  256, 0, stream>>>(D11, D11t, 512, 128,  0, 16);
  pack_w<<<nb(16384),  256, 0, stream>>>(D21, D21t, 128, 128,  0, 4);
  pack_bias<<<nb(2688), 256, 0, stream>>>(Wb, Ub, Vb, a1, a2, e10, e20, e11, e21, bias);

  marn_dma<<<NBLK, 512, 0, stream>>>(eeg, eog, UVWt, A1t, A2t,
                                     D10t, D20t, D11t, D21t, bias, (float*)d_out);
}